// Round 1
// baseline (1298.434 us; speedup 1.0000x reference)
//
#include <hip/hip_runtime.h>
#include <hip/hip_bf16.h>

#define DIM 128
#define NLAYER 4

// ---------------- CSR build ----------------

__global__ void k_count(const int* __restrict__ dst, int E, int* __restrict__ counts) {
    int e = blockIdx.x * blockDim.x + threadIdx.x;
    if (e < E) atomicAdd(&counts[dst[e]], 1);
}

__global__ __launch_bounds__(1024) void k_scan1(const int* __restrict__ in, int n,
                                                int* __restrict__ partial,
                                                int* __restrict__ blockSums) {
    __shared__ int sd[1024];
    int tid = threadIdx.x;
    int i = blockIdx.x * 1024 + tid;
    int v = (i < n) ? in[i] : 0;
    sd[tid] = v;
    __syncthreads();
    for (int off = 1; off < 1024; off <<= 1) {
        int t = (tid >= off) ? sd[tid - off] : 0;
        __syncthreads();
        sd[tid] += t;
        __syncthreads();
    }
    if (i < n) partial[i] = sd[tid];
    if (tid == 1023) blockSums[blockIdx.x] = sd[1023];
}

__global__ void k_scan2(int* __restrict__ bs, int nb) {
    // single-wave exclusive scan, nb <= 64
    int lane = threadIdx.x;
    int v = (lane < nb) ? bs[lane] : 0;
    for (int off = 1; off < 64; off <<= 1) {
        int t = __shfl_up(v, off, 64);
        if (lane >= off) v += t;
    }
    int ex = __shfl_up(v, 1, 64);
    if (lane == 0) ex = 0;
    if (lane < nb) bs[lane] = ex;
}

__global__ __launch_bounds__(1024) void k_scan3(const int* __restrict__ partial,
                                                const int* __restrict__ bs, int n,
                                                int* __restrict__ row_ptr,
                                                int* __restrict__ cursor) {
    int i = blockIdx.x * blockDim.x + threadIdx.x;
    if (i < n) {
        int v = partial[i] + bs[i >> 10];
        row_ptr[i + 1] = v;
        cursor[i + 1] = v;
    }
    if (i == 0) { row_ptr[0] = 0; cursor[0] = 0; }
}

__global__ void k_scatter(const int* __restrict__ srcA, const int* __restrict__ dstA,
                          const int* __restrict__ typA, const int* __restrict__ hopA,
                          int E, int* __restrict__ cursor, unsigned* __restrict__ csr) {
    int e = blockIdx.x * blockDim.x + threadIdx.x;
    if (e < E) {
        int d = dstA[e];
        int p = atomicAdd(&cursor[d], 1);
        // src < 50000 < 2^16, type < 4, hop < 8 -> pack in one u32
        csr[p] = (unsigned)srcA[e] | ((unsigned)typA[e] << 16) | ((unsigned)hopA[e] << 18);
    }
}

__global__ void k_bias(const float* __restrict__ b_edge, const float* __restrict__ b_hop,
                       float* __restrict__ bias_sums) {
    int t = blockIdx.x, d = threadIdx.x;
    float s = b_edge[d] + b_edge[DIM + d] + b_edge[2 * DIM + d];
    int base = t * (t + 1) / 2;
    for (int k = 1; k <= t + 1; ++k) s += b_hop[(base + k - 1) * DIM + d];
    bias_sums[t * DIM + d] = s;
}

// ---------------- batched matmul: H[s] = xsrc[s] @ W[s] ----------------

struct MMArgs {
    const float* xsrc[7];
    const float* W[7];
    float* H;   // 7 contiguous [N x 128] buffers
    int M;
};

__global__ __launch_bounds__(256) void k_matmul(MMArgs a) {
    const int s = blockIdx.y;
    const float* __restrict__ X = a.xsrc[s];
    const float* __restrict__ W = a.W[s];
    float* __restrict__ H = a.H + (size_t)s * a.M * DIM;

    __shared__ float xl[64][DIM];
    int r0 = blockIdx.x * 64;
    int tid = threadIdx.x;

    // stage 64x128 x-tile (2048 float4, 8 per thread)
    #pragma unroll
    for (int i = 0; i < 8; ++i) {
        int idx = tid + i * 256;
        int r = idx >> 5;
        int c4 = idx & 31;
        float4 v = make_float4(0.f, 0.f, 0.f, 0.f);
        if (r0 + r < a.M) v = ((const float4*)(X + (size_t)(r0 + r) * DIM))[c4];
        ((float4*)&xl[r][0])[c4] = v;
    }
    __syncthreads();

    int n = tid & 127, rh = tid >> 7;
    float acc[32];
    #pragma unroll
    for (int r = 0; r < 32; ++r) acc[r] = 0.f;

    for (int k = 0; k < DIM; k += 4) {
        float w0 = W[(k + 0) * DIM + n];
        float w1 = W[(k + 1) * DIM + n];
        float w2 = W[(k + 2) * DIM + n];
        float w3 = W[(k + 3) * DIM + n];
        #pragma unroll
        for (int r = 0; r < 32; ++r) {
            float4 xv = ((const float4*)&xl[rh * 32 + r][0])[k >> 2];
            acc[r] += xv.x * w0 + xv.y * w1 + xv.z * w2 + xv.w * w3;
        }
    }

    #pragma unroll
    for (int r = 0; r < 32; ++r) {
        int row = r0 + rh * 32 + r;
        if (row < a.M) H[(size_t)row * DIM + n] = acc[r];
    }
}

// ------- fused CSR aggregate + bias + relu + residual + L2 normalize -------

__global__ __launch_bounds__(256) void k_agg(const float* __restrict__ Hbase,
                                             const float* __restrict__ xs_in,
                                             float* __restrict__ out,
                                             const int* __restrict__ row_ptr,
                                             const unsigned* __restrict__ csr,
                                             const float* __restrict__ bias_sums,
                                             int t, int N) {
    int wid = threadIdx.x >> 6, lane = threadIdx.x & 63;
    int node = blockIdx.x * 4 + wid;
    if (node >= N) return;
    size_t NS = (size_t)N * DIM;

    float ax = 0.f, ay = 0.f;
    int e0 = row_ptr[node], e1 = row_ptr[node + 1];
    for (int e = e0; e < e1; ++e) {
        unsigned m = csr[e];
        int src = m & 0xFFFF;
        int typ = (m >> 16) & 3;
        int hop = m >> 18;
        const float2* h = (const float2*)(Hbase + (size_t)typ * NS + (size_t)src * DIM);
        float2 v = h[lane];
        ax += v.x; ay += v.y;
        if (hop >= 1 && hop <= t + 1) {   // wave-uniform branch
            const float2* h2 = (const float2*)(Hbase + (size_t)(2 + hop) * NS + (size_t)src * DIM);
            float2 v2 = h2[lane];
            ax += v2.x; ay += v2.y;
        }
    }
    float2 b  = ((const float2*)(bias_sums + t * DIM))[lane];
    float2 xv = ((const float2*)(xs_in + (size_t)node * DIM))[lane];
    float vx = xv.x + fmaxf(ax + b.x, 0.f);
    float vy = xv.y + fmaxf(ay + b.y, 0.f);
    float ss = vx * vx + vy * vy;
    #pragma unroll
    for (int off = 1; off < 64; off <<= 1) ss += __shfl_xor(ss, off, 64);
    float inv = 1.f / fmaxf(sqrtf(ss), 1e-12f);
    ((float2*)(out + (size_t)node * DIM))[lane] = make_float2(vx * inv, vy * inv);
}

// ---------------- launch ----------------

static inline size_t align_up(size_t v, size_t a) { return (v + a - 1) & ~(a - 1); }

extern "C" void kernel_launch(void* const* d_in, const int* in_sizes, int n_in,
                              void* d_out, int out_size, void* d_ws, size_t ws_size,
                              hipStream_t stream) {
    const float* x       = (const float*)d_in[0];
    const int* edge_index = (const int*)d_in[1];   // [2][E] int32
    const int* edge_hop   = (const int*)d_in[2];
    const int* edge_type  = (const int*)d_in[3];
    const float* W_edge  = (const float*)d_in[4];
    const float* b_edge  = (const float*)d_in[5];
    const float* W_hop   = (const float*)d_in[6];
    const float* b_hop   = (const float*)d_in[7];
    float* out = (float*)d_out;

    int N = in_sizes[0] / DIM;   // 50000
    int E = in_sizes[2];         // 600000
    const int* srcA = edge_index;
    const int* dstA = edge_index + E;

    size_t NSb = (size_t)N * DIM * sizeof(float);   // one node-feature buffer
    size_t off = 0;
    char* wsb = (char*)d_ws;
    float* xs1       = (float*)(wsb + off); off = align_up(off + NSb, 64);
    float* xs2       = (float*)(wsb + off); off = align_up(off + NSb, 64);
    float* Hbase     = (float*)(wsb + off); off = align_up(off + 7 * NSb, 64);
    int* counts      = (int*)(wsb + off);   off = align_up(off + (size_t)N * 4, 64);
    int* partial     = (int*)(wsb + off);   off = align_up(off + (size_t)N * 4, 64);
    int* blockSums   = (int*)(wsb + off);   off = align_up(off + 64 * 4, 64);
    int* row_ptr     = (int*)(wsb + off);   off = align_up(off + (size_t)(N + 1) * 4, 64);
    int* cursor      = (int*)(wsb + off);   off = align_up(off + (size_t)(N + 1) * 4, 64);
    unsigned* csr    = (unsigned*)(wsb + off); off = align_up(off + (size_t)E * 4, 64);
    float* bias_sums = (float*)(wsb + off); off = align_up(off + 4 * DIM * 4, 64);
    (void)ws_size;  // requires ~234 MB

    // CSR build (once per call; deterministic up to fp-add order within a node)
    hipMemsetAsync(counts, 0, (size_t)N * 4, stream);
    k_count<<<(E + 255) / 256, 256, 0, stream>>>(dstA, E, counts);
    int nb = (N + 1023) / 1024;
    k_scan1<<<nb, 1024, 0, stream>>>(counts, N, partial, blockSums);
    k_scan2<<<1, 64, 0, stream>>>(blockSums, nb);
    k_scan3<<<nb, 1024, 0, stream>>>(partial, blockSums, N, row_ptr, cursor);
    k_scatter<<<(E + 255) / 256, 256, 0, stream>>>(srcA, dstA, edge_type, edge_hop, E, cursor, csr);
    k_bias<<<4, DIM, 0, stream>>>(b_edge, b_hop, bias_sums);

    // xs[0]=input x, xs[1],xs[2] in ws, xs[3] lives in d_out (written by layer 2,
    // read+overwritten row-wise by layer 3's k_agg)
    const float* xs_ptr[4] = { x, xs1, xs2, out };

    for (int t = 0; t < NLAYER; ++t) {
        MMArgs a;
        int nsub = 3 + (t + 1);
        for (int s = 0; s < 3; ++s) {
            a.xsrc[s] = xs_ptr[t];
            a.W[s] = W_edge + (size_t)s * DIM * DIM;
        }
        int base = t * (t + 1) / 2;
        for (int j = 0; j <= t; ++j) {          // k = j+1, delay = j
            a.xsrc[3 + j] = xs_ptr[t - j];
            a.W[3 + j] = W_hop + (size_t)(base + j) * DIM * DIM;
        }
        for (int s = nsub; s < 7; ++s) { a.xsrc[s] = x; a.W[s] = W_edge; }
        a.H = Hbase; a.M = N;

        dim3 g((N + 63) / 64, nsub);
        k_matmul<<<g, 256, 0, stream>>>(a);

        float* dst_buf = (t == 3) ? out : (float*)xs_ptr[t + 1];
        k_agg<<<(N + 3) / 4, 256, 0, stream>>>(Hbase, xs_ptr[t], dst_buf,
                                               row_ptr, csr, bias_sums, t, N);
    }
}

// Round 2
// 671.298 us; speedup vs baseline: 1.9342x; 1.9342x over previous
//
#include <hip/hip_runtime.h>
#include <hip/hip_bf16.h>

#define DIM 128
#define NLAYER 4

typedef _Float16 f16x8 __attribute__((ext_vector_type(8)));
typedef _Float16 f16x2 __attribute__((ext_vector_type(2)));
typedef float f32x4 __attribute__((ext_vector_type(4)));

// ---------------- CSR build ----------------

__global__ void k_count(const int* __restrict__ dst, int E, int* __restrict__ counts) {
    int e = blockIdx.x * blockDim.x + threadIdx.x;
    if (e < E) atomicAdd(&counts[dst[e]], 1);
}

__global__ __launch_bounds__(1024) void k_scan1(const int* __restrict__ in, int n,
                                                int* __restrict__ partial,
                                                int* __restrict__ blockSums) {
    __shared__ int sd[1024];
    int tid = threadIdx.x;
    int i = blockIdx.x * 1024 + tid;
    int v = (i < n) ? in[i] : 0;
    sd[tid] = v;
    __syncthreads();
    for (int off = 1; off < 1024; off <<= 1) {
        int t = (tid >= off) ? sd[tid - off] : 0;
        __syncthreads();
        sd[tid] += t;
        __syncthreads();
    }
    if (i < n) partial[i] = sd[tid];
    if (tid == 1023) blockSums[blockIdx.x] = sd[1023];
}

__global__ void k_scan2(int* __restrict__ bs, int nb) {
    int lane = threadIdx.x;
    int v = (lane < nb) ? bs[lane] : 0;
    for (int off = 1; off < 64; off <<= 1) {
        int t = __shfl_up(v, off, 64);
        if (lane >= off) v += t;
    }
    int ex = __shfl_up(v, 1, 64);
    if (lane == 0) ex = 0;
    if (lane < nb) bs[lane] = ex;
}

__global__ __launch_bounds__(1024) void k_scan3(const int* __restrict__ partial,
                                                const int* __restrict__ bs, int n,
                                                int* __restrict__ row_ptr,
                                                int* __restrict__ cursor) {
    int i = blockIdx.x * blockDim.x + threadIdx.x;
    if (i < n) {
        int v = partial[i] + bs[i >> 10];
        row_ptr[i + 1] = v;
        cursor[i + 1] = v;
    }
    if (i == 0) { row_ptr[0] = 0; cursor[0] = 0; }
}

__global__ void k_scatter(const int* __restrict__ srcA, const int* __restrict__ dstA,
                          const int* __restrict__ typA, const int* __restrict__ hopA,
                          int E, int* __restrict__ cursor, unsigned* __restrict__ csr) {
    int e = blockIdx.x * blockDim.x + threadIdx.x;
    if (e < E) {
        int d = dstA[e];
        int p = atomicAdd(&cursor[d], 1);
        csr[p] = (unsigned)srcA[e] | ((unsigned)typA[e] << 16) | ((unsigned)hopA[e] << 18);
    }
}

__global__ void k_bias(const float* __restrict__ b_edge, const float* __restrict__ b_hop,
                       float* __restrict__ bias_sums) {
    int t = blockIdx.x, d = threadIdx.x;
    float s = b_edge[d] + b_edge[DIM + d] + b_edge[2 * DIM + d];
    int base = t * (t + 1) / 2;
    for (int k = 1; k <= t + 1; ++k) s += b_hop[(base + k - 1) * DIM + d];
    bias_sums[t * DIM + d] = s;
}

// ---------------- f16 conversions ----------------

// x (fp32) -> f16, n multiple of 8
__global__ void k_convX(const float* __restrict__ in, _Float16* __restrict__ out, int n) {
    int i = (blockIdx.x * blockDim.x + threadIdx.x) * 8;
    if (i >= n) return;
    float4 a = ((const float4*)(in + i))[0];
    float4 b = ((const float4*)(in + i))[1];
    f16x8 o;
    o[0] = (_Float16)a.x; o[1] = (_Float16)a.y; o[2] = (_Float16)a.z; o[3] = (_Float16)a.w;
    o[4] = (_Float16)b.x; o[5] = (_Float16)b.y; o[6] = (_Float16)b.z; o[7] = (_Float16)b.w;
    *(f16x8*)(out + i) = o;
}

// 13 weight matrices (3 edge + 10 hop), fp32 row-major [k][n] -> f16 transposed [n][k]
__global__ __launch_bounds__(256) void k_convW(const float* __restrict__ W_edge,
                                               const float* __restrict__ W_hop,
                                               _Float16* __restrict__ Wt) {
    int s = blockIdx.x;
    const float* src = (s < 3) ? (W_edge + (size_t)s * DIM * DIM)
                               : (W_hop + (size_t)(s - 3) * DIM * DIM);
    _Float16* dstp = Wt + (size_t)s * DIM * DIM;
    for (int it = 0; it < 64; ++it) {
        int e = it * 256 + threadIdx.x;
        int n = e >> 7, k = e & 127;
        dstp[e] = (_Float16)src[k * DIM + n];   // dst[n][k] = src[k][n]
    }
}

// ---------------- MFMA matmul: H[s] = xh[s] @ W[s], f16 in, f16 out ----------------

struct MMArgs {
    const _Float16* xh[7];
    const _Float16* Wt[7];   // transposed weights [n][k]
    _Float16* H;             // nsub contiguous [M x 128] f16 buffers
    int M;
};

__global__ __launch_bounds__(256) void k_mm(MMArgs a) {
    const int s = blockIdx.y;
    const _Float16* __restrict__ X = a.xh[s];
    const _Float16* __restrict__ B = a.Wt[s];
    _Float16* __restrict__ H = a.H + (size_t)s * a.M * DIM;

    int wv = threadIdx.x >> 6, lane = threadIdx.x & 63;
    int rowBase = blockIdx.x * 128 + wv * 32;
    int lr = lane & 15, lg = lane >> 4;

    f32x4 acc[2][8];
    #pragma unroll
    for (int rt = 0; rt < 2; ++rt)
        #pragma unroll
        for (int ct = 0; ct < 8; ++ct)
            acc[rt][ct] = (f32x4){0.f, 0.f, 0.f, 0.f};

    #pragma unroll
    for (int ks = 0; ks < 4; ++ks) {
        int kb = ks * 32 + lg * 8;
        f16x8 af[2];
        #pragma unroll
        for (int rt = 0; rt < 2; ++rt) {
            int r = rowBase + rt * 16 + lr;
            if (r >= a.M) r = a.M - 1;      // clamp; garbage rows masked at store
            af[rt] = *(const f16x8*)(X + (size_t)r * DIM + kb);
        }
        #pragma unroll
        for (int ct = 0; ct < 8; ++ct) {
            f16x8 bf = *(const f16x8*)(B + (size_t)(ct * 16 + lr) * DIM + kb);
            acc[0][ct] = __builtin_amdgcn_mfma_f32_16x16x32_f16(af[0], bf, acc[0][ct], 0, 0, 0);
            acc[1][ct] = __builtin_amdgcn_mfma_f32_16x16x32_f16(af[1], bf, acc[1][ct], 0, 0, 0);
        }
    }

    // C/D layout: col = lane&15, row = (lane>>4)*4 + reg  [m89-verified]
    #pragma unroll
    for (int rt = 0; rt < 2; ++rt) {
        #pragma unroll
        for (int ct = 0; ct < 8; ++ct) {
            #pragma unroll
            for (int rg = 0; rg < 4; ++rg) {
                int row = rowBase + rt * 16 + lg * 4 + rg;
                if (row < a.M)
                    H[(size_t)row * DIM + ct * 16 + lr] = (_Float16)acc[rt][ct][rg];
            }
        }
    }
}

// ------- fused CSR aggregate + bias + relu + residual + L2 normalize -------
// also emits the f16 copy of the output row for the next layer's matmul

__global__ __launch_bounds__(256) void k_agg(const _Float16* __restrict__ Hbase,
                                             const float* __restrict__ xs_in,
                                             float* __restrict__ out,
                                             _Float16* __restrict__ xh_out,
                                             const int* __restrict__ row_ptr,
                                             const unsigned* __restrict__ csr,
                                             const float* __restrict__ bias_sums,
                                             int t, int N) {
    int wid = threadIdx.x >> 6, lane = threadIdx.x & 63;
    int node = blockIdx.x * 4 + wid;
    if (node >= N) return;
    size_t NS = (size_t)N * DIM;

    float ax = 0.f, ay = 0.f;
    int e0 = row_ptr[node], e1 = row_ptr[node + 1];
    for (int e = e0; e < e1; ++e) {
        unsigned m = csr[e];
        int src = m & 0xFFFF;
        int typ = (m >> 16) & 3;
        int hop = m >> 18;
        f16x2 v = ((const f16x2*)(Hbase + (size_t)typ * NS + (size_t)src * DIM))[lane];
        ax += (float)v[0]; ay += (float)v[1];
        if (hop >= 1 && hop <= t + 1) {
            f16x2 v2 = ((const f16x2*)(Hbase + (size_t)(2 + hop) * NS + (size_t)src * DIM))[lane];
            ax += (float)v2[0]; ay += (float)v2[1];
        }
    }
    float2 b  = ((const float2*)(bias_sums + t * DIM))[lane];
    float2 xv = ((const float2*)(xs_in + (size_t)node * DIM))[lane];
    float vx = xv.x + fmaxf(ax + b.x, 0.f);
    float vy = xv.y + fmaxf(ay + b.y, 0.f);
    float ss = vx * vx + vy * vy;
    #pragma unroll
    for (int off = 1; off < 64; off <<= 1) ss += __shfl_xor(ss, off, 64);
    float inv = 1.f / fmaxf(sqrtf(ss), 1e-12f);
    vx *= inv; vy *= inv;
    ((float2*)(out + (size_t)node * DIM))[lane] = make_float2(vx, vy);
    if (xh_out) {
        f16x2 o; o[0] = (_Float16)vx; o[1] = (_Float16)vy;
        ((f16x2*)(xh_out + (size_t)node * DIM))[lane] = o;
    }
}

// ---------------- launch ----------------

static inline size_t align_up(size_t v, size_t a) { return (v + a - 1) & ~(a - 1); }

extern "C" void kernel_launch(void* const* d_in, const int* in_sizes, int n_in,
                              void* d_out, int out_size, void* d_ws, size_t ws_size,
                              hipStream_t stream) {
    const float* x        = (const float*)d_in[0];
    const int* edge_index = (const int*)d_in[1];
    const int* edge_hop   = (const int*)d_in[2];
    const int* edge_type  = (const int*)d_in[3];
    const float* W_edge   = (const float*)d_in[4];
    const float* b_edge   = (const float*)d_in[5];
    const float* W_hop    = (const float*)d_in[6];
    const float* b_hop    = (const float*)d_in[7];
    float* out = (float*)d_out;

    int N = in_sizes[0] / DIM;   // 50000
    int E = in_sizes[2];         // 600000
    const int* srcA = edge_index;
    const int* dstA = edge_index + E;

    size_t NSf = (size_t)N * DIM * sizeof(float);     // fp32 node buffer
    size_t NSh = (size_t)N * DIM * sizeof(_Float16);  // f16 node buffer
    size_t off = 0;
    char* wsb = (char*)d_ws;
    float* xs1        = (float*)(wsb + off);     off = align_up(off + NSf, 64);
    float* xs2        = (float*)(wsb + off);     off = align_up(off + NSf, 64);
    _Float16* Hbase   = (_Float16*)(wsb + off);  off = align_up(off + 7 * NSh, 64);
    _Float16* xh0     = (_Float16*)(wsb + off);  off = align_up(off + NSh, 64);
    _Float16* xh1     = (_Float16*)(wsb + off);  off = align_up(off + NSh, 64);
    _Float16* xh2     = (_Float16*)(wsb + off);  off = align_up(off + NSh, 64);
    _Float16* xh3     = (_Float16*)(wsb + off);  off = align_up(off + NSh, 64);
    _Float16* Wt      = (_Float16*)(wsb + off);  off = align_up(off + 13 * DIM * DIM * sizeof(_Float16), 64);
    int* counts       = (int*)(wsb + off);       off = align_up(off + (size_t)N * 4, 64);
    int* partial      = (int*)(wsb + off);       off = align_up(off + (size_t)N * 4, 64);
    int* blockSums    = (int*)(wsb + off);       off = align_up(off + 64 * 4, 64);
    int* row_ptr      = (int*)(wsb + off);       off = align_up(off + (size_t)(N + 1) * 4, 64);
    int* cursor       = (int*)(wsb + off);       off = align_up(off + (size_t)(N + 1) * 4, 64);
    unsigned* csr     = (unsigned*)(wsb + off);  off = align_up(off + (size_t)E * 4, 64);
    float* bias_sums  = (float*)(wsb + off);     off = align_up(off + 4 * DIM * 4, 64);
    (void)ws_size;  // ~196 MB

    // CSR build
    hipMemsetAsync(counts, 0, (size_t)N * 4, stream);
    k_count<<<(E + 255) / 256, 256, 0, stream>>>(dstA, E, counts);
    int nb = (N + 1023) / 1024;
    k_scan1<<<nb, 1024, 0, stream>>>(counts, N, partial, blockSums);
    k_scan2<<<1, 64, 0, stream>>>(blockSums, nb);
    k_scan3<<<nb, 1024, 0, stream>>>(partial, blockSums, N, row_ptr, cursor);
    k_scatter<<<(E + 255) / 256, 256, 0, stream>>>(srcA, dstA, edge_type, edge_hop, E, cursor, csr);
    k_bias<<<4, DIM, 0, stream>>>(b_edge, b_hop, bias_sums);

    // f16 conversions
    k_convX<<<(N * DIM / 8 + 255) / 256, 256, 0, stream>>>(x, xh0, N * DIM);
    k_convW<<<13, 256, 0, stream>>>(W_edge, W_hop, Wt);

    const float* xs_ptr[4] = { x, xs1, xs2, out };
    _Float16* xh_ptr[4] = { xh0, xh1, xh2, xh3 };

    for (int t = 0; t < NLAYER; ++t) {
        MMArgs a;
        int nsub = 3 + (t + 1);
        for (int s = 0; s < 3; ++s) {
            a.xh[s] = xh_ptr[t];
            a.Wt[s] = Wt + (size_t)s * DIM * DIM;
        }
        int base = t * (t + 1) / 2;
        for (int j = 0; j <= t; ++j) {          // k = j+1, delay = j
            a.xh[3 + j] = xh_ptr[t - j];
            a.Wt[3 + j] = Wt + (size_t)(3 + base + j) * DIM * DIM;
        }
        for (int s = nsub; s < 7; ++s) { a.xh[s] = xh0; a.Wt[s] = Wt; }
        a.H = Hbase; a.M = N;

        dim3 g((N + 127) / 128, nsub);
        k_mm<<<g, 256, 0, stream>>>(a);

        float* dst_buf = (t == 3) ? out : (float*)xs_ptr[t + 1];
        _Float16* xh_dst = (t == 3) ? (_Float16*)nullptr : xh_ptr[t + 1];
        k_agg<<<(N + 3) / 4, 256, 0, stream>>>(Hbase, xs_ptr[t], dst_buf, xh_dst,
                                               row_ptr, csr, bias_sums, t, N);
    }
}

// Round 3
// 662.348 us; speedup vs baseline: 1.9604x; 1.0135x over previous
//
#include <hip/hip_runtime.h>
#include <hip/hip_bf16.h>

#define DIM 128
#define NLAYER 4

typedef _Float16 f16x8 __attribute__((ext_vector_type(8)));
typedef _Float16 f16x2 __attribute__((ext_vector_type(2)));
typedef float f32x4 __attribute__((ext_vector_type(4)));

// ---------------- CSR build ----------------

__global__ void k_count(const int* __restrict__ dst, int E, int* __restrict__ counts) {
    int e = blockIdx.x * blockDim.x + threadIdx.x;
    if (e < E) atomicAdd(&counts[dst[e]], 1);
}

__global__ __launch_bounds__(1024) void k_scan1(const int* __restrict__ in, int n,
                                                int* __restrict__ partial,
                                                int* __restrict__ blockSums) {
    __shared__ int sd[1024];
    int tid = threadIdx.x;
    int i = blockIdx.x * 1024 + tid;
    int v = (i < n) ? in[i] : 0;
    sd[tid] = v;
    __syncthreads();
    for (int off = 1; off < 1024; off <<= 1) {
        int t = (tid >= off) ? sd[tid - off] : 0;
        __syncthreads();
        sd[tid] += t;
        __syncthreads();
    }
    if (i < n) partial[i] = sd[tid];
    if (tid == 1023) blockSums[blockIdx.x] = sd[1023];
}

__global__ void k_scan2(int* __restrict__ bs, int nb) {
    int lane = threadIdx.x;
    int v = (lane < nb) ? bs[lane] : 0;
    for (int off = 1; off < 64; off <<= 1) {
        int t = __shfl_up(v, off, 64);
        if (lane >= off) v += t;
    }
    int ex = __shfl_up(v, 1, 64);
    if (lane == 0) ex = 0;
    if (lane < nb) bs[lane] = ex;
}

__global__ __launch_bounds__(1024) void k_scan3(const int* __restrict__ partial,
                                                const int* __restrict__ bs, int n,
                                                int* __restrict__ row_ptr,
                                                int* __restrict__ cursor) {
    int i = blockIdx.x * blockDim.x + threadIdx.x;
    if (i < n) {
        int v = partial[i] + bs[i >> 10];
        row_ptr[i + 1] = v;
        cursor[i + 1] = v;
    }
    if (i == 0) { row_ptr[0] = 0; cursor[0] = 0; }
}

__global__ void k_scatter(const int* __restrict__ srcA, const int* __restrict__ dstA,
                          const int* __restrict__ typA, const int* __restrict__ hopA,
                          int E, int* __restrict__ cursor, unsigned* __restrict__ csr) {
    int e = blockIdx.x * blockDim.x + threadIdx.x;
    if (e < E) {
        int d = dstA[e];
        int p = atomicAdd(&cursor[d], 1);
        csr[p] = (unsigned)srcA[e] | ((unsigned)typA[e] << 16) | ((unsigned)hopA[e] << 18);
    }
}

__global__ void k_bias(const float* __restrict__ b_edge, const float* __restrict__ b_hop,
                       float* __restrict__ bias_sums) {
    int t = blockIdx.x, d = threadIdx.x;
    float s = b_edge[d] + b_edge[DIM + d] + b_edge[2 * DIM + d];
    int base = t * (t + 1) / 2;
    for (int k = 1; k <= t + 1; ++k) s += b_hop[(base + k - 1) * DIM + d];
    bias_sums[t * DIM + d] = s;
}

// ---------------- f16 conversions ----------------

__global__ void k_convX(const float* __restrict__ in, _Float16* __restrict__ out, int n) {
    int i = (blockIdx.x * blockDim.x + threadIdx.x) * 8;
    if (i >= n) return;
    float4 a = ((const float4*)(in + i))[0];
    float4 b = ((const float4*)(in + i))[1];
    f16x8 o;
    o[0] = (_Float16)a.x; o[1] = (_Float16)a.y; o[2] = (_Float16)a.z; o[3] = (_Float16)a.w;
    o[4] = (_Float16)b.x; o[5] = (_Float16)b.y; o[6] = (_Float16)b.z; o[7] = (_Float16)b.w;
    *(f16x8*)(out + i) = o;
}

// 13 weight matrices, fp32 row-major [k][n] -> f16 transposed [n][k]
__global__ __launch_bounds__(256) void k_convW(const float* __restrict__ W_edge,
                                               const float* __restrict__ W_hop,
                                               _Float16* __restrict__ Wt) {
    int s = blockIdx.x;
    const float* src = (s < 3) ? (W_edge + (size_t)s * DIM * DIM)
                               : (W_hop + (size_t)(s - 3) * DIM * DIM);
    _Float16* dstp = Wt + (size_t)s * DIM * DIM;
    for (int it = 0; it < 64; ++it) {
        int e = it * 256 + threadIdx.x;
        int n = e >> 7, k = e & 127;
        dstp[e] = (_Float16)src[k * DIM + n];
    }
}

// -------- phase 1: CSR gather-aggregate x rows into per-sublayer A rows --------
// A slot map: 0..2 = edge types, 3+(k-1) = hop k (k=1..t+1)

struct GatherArgs {
    const _Float16* xt;    // xh[t]   (types + hop1)
    const _Float16* xm1;   // xh[t-1] (hop2)
    const _Float16* xm2;   // xh[t-2] (hop3)
    const _Float16* xm3;   // xh[t-3] (hop4)
    _Float16* A;           // [7][N][128]
    const int* row_ptr;
    const unsigned* csr;
    int t, N;
};

__global__ __launch_bounds__(256) void k_gather(GatherArgs a) {
    int wid = threadIdx.x >> 6, lane = threadIdx.x & 63;
    int node = blockIdx.x * 4 + wid;
    if (node >= a.N) return;
    size_t NS = (size_t)a.N * DIM;

    float t0x = 0, t0y = 0, t1x = 0, t1y = 0, t2x = 0, t2y = 0;
    float h1x = 0, h1y = 0, h2x = 0, h2y = 0, h3x = 0, h3y = 0, h4x = 0, h4y = 0;

    int e0 = a.row_ptr[node], e1 = a.row_ptr[node + 1];
    for (int e = e0; e < e1; ++e) {
        unsigned m = a.csr[e];
        int src = m & 0xFFFF;
        int typ = (m >> 16) & 3;
        int hop = m >> 18;
        f16x2 v = ((const f16x2*)(a.xt + (size_t)src * DIM))[lane];
        float vx = (float)v[0], vy = (float)v[1];
        if (typ == 0)      { t0x += vx; t0y += vy; }
        else if (typ == 1) { t1x += vx; t1y += vy; }
        else               { t2x += vx; t2y += vy; }
        if (hop == 1) { h1x += vx; h1y += vy; }
        else if (hop >= 2 && hop <= a.t + 1) {
            const _Float16* p = (hop == 2) ? a.xm1 : (hop == 3) ? a.xm2 : a.xm3;
            f16x2 w = ((const f16x2*)(p + (size_t)src * DIM))[lane];
            float wx = (float)w[0], wy = (float)w[1];
            if (hop == 2)      { h2x += wx; h2y += wy; }
            else if (hop == 3) { h3x += wx; h3y += wy; }
            else               { h4x += wx; h4y += wy; }
        }
    }

    _Float16* base = a.A + (size_t)node * DIM;
    f16x2 o;
    o[0] = (_Float16)t0x; o[1] = (_Float16)t0y; ((f16x2*)(base + 0 * NS))[lane] = o;
    o[0] = (_Float16)t1x; o[1] = (_Float16)t1y; ((f16x2*)(base + 1 * NS))[lane] = o;
    o[0] = (_Float16)t2x; o[1] = (_Float16)t2y; ((f16x2*)(base + 2 * NS))[lane] = o;
    o[0] = (_Float16)h1x; o[1] = (_Float16)h1y; ((f16x2*)(base + 3 * NS))[lane] = o;
    if (a.t >= 1) { o[0] = (_Float16)h2x; o[1] = (_Float16)h2y; ((f16x2*)(base + 4 * NS))[lane] = o; }
    if (a.t >= 2) { o[0] = (_Float16)h3x; o[1] = (_Float16)h3y; ((f16x2*)(base + 5 * NS))[lane] = o; }
    if (a.t >= 3) { o[0] = (_Float16)h4x; o[1] = (_Float16)h4y; ((f16x2*)(base + 6 * NS))[lane] = o; }
}

// -------- phase 2: C = sum_s A_s @ W_s, fused bias+relu+residual+L2norm --------

struct GemmArgs {
    const _Float16* A;     // [7][N][128]
    const _Float16* Wt;    // 13 x [n][k] f16
    const _Float16* xin;   // xh[t], residual source
    const float* bias;     // bias_sums + t*128
    float* outf;           // fp32 out (final layer) or null
    _Float16* outh;        // xh[t+1] or null
    int nsub, N;
    int wsel[7];
};

__global__ __launch_bounds__(256) void k_gemm(GemmArgs a) {
    int wv = threadIdx.x >> 6, lane = threadIdx.x & 63;
    int rowBase = blockIdx.x * 128 + wv * 32;
    int lr = lane & 15, lg = lane >> 4;
    size_t NS = (size_t)a.N * DIM;

    f32x4 acc[2][8];
    #pragma unroll
    for (int rt = 0; rt < 2; ++rt)
        #pragma unroll
        for (int ct = 0; ct < 8; ++ct)
            acc[rt][ct] = (f32x4){0.f, 0.f, 0.f, 0.f};

    for (int s = 0; s < a.nsub; ++s) {
        const _Float16* As = a.A + (size_t)s * NS;
        const _Float16* Bs = a.Wt + (size_t)a.wsel[s] * (DIM * DIM);
        #pragma unroll
        for (int ks = 0; ks < 4; ++ks) {
            int kb = ks * 32 + lg * 8;
            f16x8 af[2];
            #pragma unroll
            for (int rt = 0; rt < 2; ++rt) {
                int r = rowBase + rt * 16 + lr;
                if (r >= a.N) r = a.N - 1;
                af[rt] = *(const f16x8*)(As + (size_t)r * DIM + kb);
            }
            #pragma unroll
            for (int ct = 0; ct < 8; ++ct) {
                f16x8 bf = *(const f16x8*)(Bs + (size_t)(ct * 16 + lr) * DIM + kb);
                acc[0][ct] = __builtin_amdgcn_mfma_f32_16x16x32_f16(af[0], bf, acc[0][ct], 0, 0, 0);
                acc[1][ct] = __builtin_amdgcn_mfma_f32_16x16x32_f16(af[1], bf, acc[1][ct], 0, 0, 0);
            }
        }
    }

    float bv[8];
    #pragma unroll
    for (int ct = 0; ct < 8; ++ct) bv[ct] = a.bias[ct * 16 + lr];

    // C/D layout: col = lane&15, row = (lane>>4)*4 + reg
    #pragma unroll
    for (int rt = 0; rt < 2; ++rt) {
        #pragma unroll
        for (int rg = 0; rg < 4; ++rg) {
            int row = rowBase + rt * 16 + lg * 4 + rg;
            int rr = (row < a.N) ? row : a.N - 1;
            float v[8];
            float ss = 0.f;
            #pragma unroll
            for (int ct = 0; ct < 8; ++ct) {
                float xval = (float)a.xin[(size_t)rr * DIM + ct * 16 + lr];
                float tv = fmaxf(acc[rt][ct][rg] + bv[ct], 0.f) + xval;
                v[ct] = tv;
                ss += tv * tv;
            }
            ss += __shfl_xor(ss, 1, 64);
            ss += __shfl_xor(ss, 2, 64);
            ss += __shfl_xor(ss, 4, 64);
            ss += __shfl_xor(ss, 8, 64);
            float inv = 1.f / fmaxf(sqrtf(ss), 1e-12f);
            if (row < a.N) {
                #pragma unroll
                for (int ct = 0; ct < 8; ++ct) {
                    int col = ct * 16 + lr;
                    float ov = v[ct] * inv;
                    if (a.outf) a.outf[(size_t)row * DIM + col] = ov;
                    if (a.outh) a.outh[(size_t)row * DIM + col] = (_Float16)ov;
                }
            }
        }
    }
}

// ---------------- launch ----------------

static inline size_t align_up(size_t v, size_t a) { return (v + a - 1) & ~(a - 1); }

extern "C" void kernel_launch(void* const* d_in, const int* in_sizes, int n_in,
                              void* d_out, int out_size, void* d_ws, size_t ws_size,
                              hipStream_t stream) {
    const float* x        = (const float*)d_in[0];
    const int* edge_index = (const int*)d_in[1];
    const int* edge_hop   = (const int*)d_in[2];
    const int* edge_type  = (const int*)d_in[3];
    const float* W_edge   = (const float*)d_in[4];
    const float* b_edge   = (const float*)d_in[5];
    const float* W_hop    = (const float*)d_in[6];
    const float* b_hop    = (const float*)d_in[7];
    float* out = (float*)d_out;

    int N = in_sizes[0] / DIM;   // 50000
    int E = in_sizes[2];         // 600000
    const int* srcA = edge_index;
    const int* dstA = edge_index + E;

    size_t NSh = (size_t)N * DIM * sizeof(_Float16);
    size_t off = 0;
    char* wsb = (char*)d_ws;
    _Float16* xh0     = (_Float16*)(wsb + off);  off = align_up(off + NSh, 64);
    _Float16* xh1     = (_Float16*)(wsb + off);  off = align_up(off + NSh, 64);
    _Float16* xh2     = (_Float16*)(wsb + off);  off = align_up(off + NSh, 64);
    _Float16* xh3     = (_Float16*)(wsb + off);  off = align_up(off + NSh, 64);
    _Float16* A       = (_Float16*)(wsb + off);  off = align_up(off + 7 * NSh, 64);
    _Float16* Wt      = (_Float16*)(wsb + off);  off = align_up(off + 13 * DIM * DIM * sizeof(_Float16), 64);
    int* counts       = (int*)(wsb + off);       off = align_up(off + (size_t)N * 4, 64);
    int* partial      = (int*)(wsb + off);       off = align_up(off + (size_t)N * 4, 64);
    int* blockSums    = (int*)(wsb + off);       off = align_up(off + 64 * 4, 64);
    int* row_ptr      = (int*)(wsb + off);       off = align_up(off + (size_t)(N + 1) * 4, 64);
    int* cursor       = (int*)(wsb + off);       off = align_up(off + (size_t)(N + 1) * 4, 64);
    unsigned* csr     = (unsigned*)(wsb + off);  off = align_up(off + (size_t)E * 4, 64);
    float* bias_sums  = (float*)(wsb + off);     off = align_up(off + 4 * DIM * 4, 64);
    (void)ws_size;  // ~146 MB

    // CSR build
    hipMemsetAsync(counts, 0, (size_t)N * 4, stream);
    k_count<<<(E + 255) / 256, 256, 0, stream>>>(dstA, E, counts);
    int nb = (N + 1023) / 1024;
    k_scan1<<<nb, 1024, 0, stream>>>(counts, N, partial, blockSums);
    k_scan2<<<1, 64, 0, stream>>>(blockSums, nb);
    k_scan3<<<nb, 1024, 0, stream>>>(partial, blockSums, N, row_ptr, cursor);
    k_scatter<<<(E + 255) / 256, 256, 0, stream>>>(srcA, dstA, edge_type, edge_hop, E, cursor, csr);
    k_bias<<<4, DIM, 0, stream>>>(b_edge, b_hop, bias_sums);

    // f16 conversions
    k_convX<<<(N * DIM / 8 + 255) / 256, 256, 0, stream>>>(x, xh0, N * DIM);
    k_convW<<<13, 256, 0, stream>>>(W_edge, W_hop, Wt);

    _Float16* xh_ptr[4] = { xh0, xh1, xh2, xh3 };

    for (int t = 0; t < NLAYER; ++t) {
        GatherArgs g;
        g.xt  = xh_ptr[t];
        g.xm1 = (t >= 1) ? xh_ptr[t - 1] : xh0;
        g.xm2 = (t >= 2) ? xh_ptr[t - 2] : xh0;
        g.xm3 = (t >= 3) ? xh_ptr[t - 3] : xh0;
        g.A = A; g.row_ptr = row_ptr; g.csr = csr; g.t = t; g.N = N;
        k_gather<<<(N + 3) / 4, 256, 0, stream>>>(g);

        GemmArgs m;
        m.A = A; m.Wt = Wt; m.xin = xh_ptr[t];
        m.bias = bias_sums + t * DIM;
        m.outf = (t == 3) ? out : nullptr;
        m.outh = (t < 3) ? xh_ptr[t + 1] : nullptr;
        m.nsub = t + 4; m.N = N;
        int base = t * (t + 1) / 2;
        for (int s = 0; s < 3; ++s) m.wsel[s] = s;
        for (int j = 0; j <= t; ++j) m.wsel[3 + j] = 3 + base + j;
        for (int s = m.nsub; s < 7; ++s) m.wsel[s] = 0;
        k_gemm<<<(N + 127) / 128, 256, 0, stream>>>(m);
    }
}